// Round 1
// baseline (166.359 us; speedup 1.0000x reference)
//
#include <hip/hip_runtime.h>
#include <hip/hip_bf16.h>

// ---- problem constants ----
#define BATCH   4096
#define FEAT    1024
#define NTREES  10
#define NNODES  255
#define NLEAF   256
#define NCLS    1000
#define NCLSP   1024          // padded classes
#define KTOT    (NTREES*NLEAF) // 2560 = GEMM2 K

typedef __attribute__((ext_vector_type(8))) short  bf16x8;
typedef __attribute__((ext_vector_type(4))) float  f32x4;

// workspace layout (bytes)
#define OFF_XB 0u                         // x bf16 [4096][1024]            8,388,608
#define OFF_WT 8388608u                   // wT bf16 [10][256][1024]        5,242,880
#define OFF_PT 13631488u                  // pT bf16 [1024][2560]           5,242,880
#define OFF_RT 18874368u                  // route bf16 [4096][2560]       20,971,520
// total 39,845,888

__device__ __forceinline__ void load_lds16(const void* g, void* l) {
    __builtin_amdgcn_global_load_lds(
        (const __attribute__((address_space(1))) unsigned int*)g,
        (__attribute__((address_space(3))) unsigned int*)l, 16, 0, 0);
}

// ---------------- conversion kernels ----------------

__global__ void k_cvt_x(const float* __restrict__ x, __hip_bfloat16* __restrict__ xb) {
    int i = blockIdx.x * 256 + threadIdx.x;   // 1,048,576 threads, 4 floats each
    float4 v = reinterpret_cast<const float4*>(x)[i];
    union { ushort4 u; __hip_bfloat16 h[4]; } o;
    o.h[0] = __float2bfloat16(v.x);
    o.h[1] = __float2bfloat16(v.y);
    o.h[2] = __float2bfloat16(v.z);
    o.h[3] = __float2bfloat16(v.w);
    reinterpret_cast<ushort4*>(xb)[i] = o.u;
}

// w[t][f][255] (f-major) -> wT[t][n(256,pad)][f] bf16
__global__ void k_cvt_w(const float* __restrict__ w, __hip_bfloat16* __restrict__ wT) {
    __shared__ float tile[32][33];
    int t  = blockIdx.z;
    int nb = blockIdx.x * 32;      // 8 tiles
    int fb = blockIdx.y * 32;      // 32 tiles
    int tx = threadIdx.x & 31, ty = threadIdx.x >> 5;   // 32 x 8
#pragma unroll
    for (int j = 0; j < 4; ++j) {
        int f = fb + ty + j * 8;
        int n = nb + tx;
        float v = (n < NNODES) ? w[((size_t)t * FEAT + f) * NNODES + n] : 0.f;
        tile[ty + j * 8][tx] = v;
    }
    __syncthreads();
#pragma unroll
    for (int j = 0; j < 4; ++j) {
        int n = nb + ty + j * 8;
        int f = fb + tx;
        wT[((size_t)t * NLEAF + n) * FEAT + f] = __float2bfloat16(tile[tx][ty + j * 8]);
    }
}

// p[k(2560)][c(1000)] -> pT[c(1024,pad)][k], pre-scaled by 1/NTREES
__global__ void k_cvt_p(const float* __restrict__ p, __hip_bfloat16* __restrict__ pT) {
    __shared__ float tile[32][33];
    int cb = blockIdx.x * 32;      // 32 tiles
    int kb = blockIdx.y * 32;      // 80 tiles
    int tx = threadIdx.x & 31, ty = threadIdx.x >> 5;
#pragma unroll
    for (int j = 0; j < 4; ++j) {
        int k = kb + ty + j * 8;
        int c = cb + tx;
        float v = (c < NCLS) ? p[(size_t)k * NCLS + c] * 0.1f : 0.f;
        tile[ty + j * 8][tx] = v;
    }
    __syncthreads();
#pragma unroll
    for (int j = 0; j < 4; ++j) {
        int c = cb + ty + j * 8;
        int k = kb + tx;
        pT[(size_t)c * KTOT + k] = __float2bfloat16(tile[tx][ty + j * 8]);
    }
}

// ---------------- GEMM1 + sigmoid + routing ----------------
// block: 128 batch rows x 256 nodes (one full tree), K=1024, BK=64
// 512 threads = 8 waves as 2(M) x 4(N), wave tile 64x64
__global__ __launch_bounds__(512) void k_gemm1_route(
        const __hip_bfloat16* __restrict__ xb,
        const __hip_bfloat16* __restrict__ wT,
        __hip_bfloat16* __restrict__ route) {
    __shared__ __align__(16) char smem[65536];
    __hip_bfloat16* As = (__hip_bfloat16*)smem;            // [128][64]
    __hip_bfloat16* Bs = (__hip_bfloat16*)(smem + 16384);  // [256][64]
    float* Ds = (float*)smem;                              // [64][256] epilogue

    const int t   = blockIdx.y;
    const int bm  = blockIdx.x;
    const int tid = threadIdx.x;
    const int lane = tid & 63, wid = tid >> 6;
    const int wm = wid >> 2, wn = wid & 3;
    const int lrow = lane >> 3, lcol = lane & 7;

    f32x4 acc[4][4] = {};

    const __hip_bfloat16* Ag = xb + (size_t)(bm * 128) * FEAT;
    const __hip_bfloat16* Bg = wT + (size_t)t * NLEAF * FEAT;

    for (int k0 = 0; k0 < FEAT; k0 += 64) {
        // stage A: 16 KB -> 8 waves x 2 issues
#pragma unroll
        for (int q = 0; q < 2; ++q) {
            int rowl = (wid * 2 + q) * 8 + lrow;             // 0..127
            load_lds16(Ag + (size_t)rowl * FEAT + k0 + lcol * 8,
                       smem + (wid * 2 + q) * 1024);
        }
        // stage B: 32 KB -> 8 waves x 4 issues
#pragma unroll
        for (int q = 0; q < 4; ++q) {
            int rowl = (wid * 4 + q) * 8 + lrow;             // 0..255
            load_lds16(Bg + (size_t)rowl * FEAT + k0 + lcol * 8,
                       smem + 16384 + (wid * 4 + q) * 1024);
        }
        __syncthreads();
#pragma unroll
        for (int ks = 0; ks < 2; ++ks) {
            bf16x8 a[4], b[4];
            int col = ks * 32 + (lane >> 4) * 8;
#pragma unroll
            for (int mf = 0; mf < 4; ++mf) {
                int row = wm * 64 + mf * 16 + (lane & 15);
                a[mf] = *(const bf16x8*)(As + row * 64 + col);
            }
#pragma unroll
            for (int nf = 0; nf < 4; ++nf) {
                int row = wn * 64 + nf * 16 + (lane & 15);
                b[nf] = *(const bf16x8*)(Bs + row * 64 + col);
            }
#pragma unroll
            for (int mf = 0; mf < 4; ++mf)
#pragma unroll
                for (int nf = 0; nf < 4; ++nf)
                    acc[mf][nf] = __builtin_amdgcn_mfma_f32_16x16x32_bf16(
                        a[mf], b[nf], acc[mf][nf], 0, 0, 0);
        }
        __syncthreads();
    }

    // epilogue: sigmoid -> LDS (fp32, 64 rows at a time) -> routing -> route bf16
    for (int half = 0; half < 2; ++half) {
        if (wm == half) {
#pragma unroll
            for (int mf = 0; mf < 4; ++mf)
#pragma unroll
                for (int nf = 0; nf < 4; ++nf)
#pragma unroll
                    for (int r = 0; r < 4; ++r) {
                        int row = mf * 16 + (lane >> 4) * 4 + r;      // 0..63
                        int col = wn * 64 + nf * 16 + (lane & 15);
                        float z = acc[mf][nf][r];
                        Ds[row * 256 + col] = 1.f / (1.f + __expf(-z));
                    }
        }
        __syncthreads();
#pragma unroll
        for (int rr = 0; rr < 8; ++rr) {
            int row = wid * 8 + rr;                                    // 0..63
#pragma unroll
            for (int cc = 0; cc < 4; ++cc) {
                int leaf = cc * 64 + lane;
                float prod = 1.f;
#pragma unroll
                for (int l = 0; l < 8; ++l) {
                    int nidx = (1 << l) - 1 + (leaf >> (8 - l));
                    float v = Ds[row * 256 + nidx];
                    prod *= (((leaf >> (7 - l)) & 1) == 0) ? v : (1.f - v);
                }
                int b = bm * 128 + half * 64 + row;
                route[(size_t)b * KTOT + t * NLEAF + leaf] = __float2bfloat16(prod);
            }
        }
        __syncthreads();
    }
}

// ---------------- GEMM2 + clip ----------------
// block: 128 x 128, K=2560, BK=64; 256 threads = 4 waves as 2x2
__global__ __launch_bounds__(256) void k_gemm2(
        const __hip_bfloat16* __restrict__ route,
        const __hip_bfloat16* __restrict__ pT,
        float* __restrict__ out) {
    __shared__ __align__(16) char smem[32768];
    __hip_bfloat16* As = (__hip_bfloat16*)smem;            // [128][64]
    __hip_bfloat16* Bs = (__hip_bfloat16*)(smem + 16384);  // [128][64]

    const int bm = blockIdx.x;   // 32
    const int bn = blockIdx.y;   // 8
    const int tid = threadIdx.x;
    const int lane = tid & 63, wid = tid >> 6;
    const int wm = wid >> 1, wn = wid & 1;
    const int lrow = lane >> 3, lcol = lane & 7;

    f32x4 acc[4][4] = {};

    for (int k0 = 0; k0 < KTOT; k0 += 64) {
#pragma unroll
        for (int q = 0; q < 4; ++q) {
            int rowl = (wid * 4 + q) * 8 + lrow;             // 0..127
            load_lds16(route + (size_t)(bm * 128 + rowl) * KTOT + k0 + lcol * 8,
                       smem + (wid * 4 + q) * 1024);
        }
#pragma unroll
        for (int q = 0; q < 4; ++q) {
            int rowl = (wid * 4 + q) * 8 + lrow;             // 0..127
            load_lds16(pT + (size_t)(bn * 128 + rowl) * KTOT + k0 + lcol * 8,
                       smem + 16384 + (wid * 4 + q) * 1024);
        }
        __syncthreads();
#pragma unroll
        for (int ks = 0; ks < 2; ++ks) {
            bf16x8 a[4], b[4];
            int col = ks * 32 + (lane >> 4) * 8;
#pragma unroll
            for (int mf = 0; mf < 4; ++mf) {
                int row = wm * 64 + mf * 16 + (lane & 15);
                a[mf] = *(const bf16x8*)(As + row * 64 + col);
            }
#pragma unroll
            for (int nf = 0; nf < 4; ++nf) {
                int row = wn * 64 + nf * 16 + (lane & 15);
                b[nf] = *(const bf16x8*)(Bs + row * 64 + col);
            }
#pragma unroll
            for (int mf = 0; mf < 4; ++mf)
#pragma unroll
                for (int nf = 0; nf < 4; ++nf)
                    acc[mf][nf] = __builtin_amdgcn_mfma_f32_16x16x32_bf16(
                        a[mf], b[nf], acc[mf][nf], 0, 0, 0);
        }
        __syncthreads();
    }

    // clip + masked store (output is 1000 wide)
#pragma unroll
    for (int mf = 0; mf < 4; ++mf)
#pragma unroll
        for (int nf = 0; nf < 4; ++nf)
#pragma unroll
            for (int r = 0; r < 4; ++r) {
                int row = bm * 128 + wm * 64 + mf * 16 + (lane >> 4) * 4 + r;
                int col = bn * 128 + wn * 64 + nf * 16 + (lane & 15);
                if (col < NCLS) {
                    float v = acc[mf][nf][r];
                    v = fminf(fmaxf(v, 0.f), 1.f);
                    out[(size_t)row * NCLS + col] = v;
                }
            }
}

extern "C" void kernel_launch(void* const* d_in, const int* in_sizes, int n_in,
                              void* d_out, int out_size, void* d_ws, size_t ws_size,
                              hipStream_t stream) {
    const float* x = (const float*)d_in[0];   // [4096][1024]
    const float* w = (const float*)d_in[1];   // [10][1024][255]
    const float* p = (const float*)d_in[2];   // [10][256][1000]
    float* out = (float*)d_out;               // [4096][1000]
    char* ws = (char*)d_ws;

    __hip_bfloat16* xb    = (__hip_bfloat16*)(ws + OFF_XB);
    __hip_bfloat16* wT    = (__hip_bfloat16*)(ws + OFF_WT);
    __hip_bfloat16* pT    = (__hip_bfloat16*)(ws + OFF_PT);
    __hip_bfloat16* route = (__hip_bfloat16*)(ws + OFF_RT);

    k_cvt_x<<<4096, 256, 0, stream>>>(x, xb);
    k_cvt_w<<<dim3(8, 32, 10), 256, 0, stream>>>(w, wT);
    k_cvt_p<<<dim3(32, 80), 256, 0, stream>>>(p, pT);
    k_gemm1_route<<<dim3(32, 10), 512, 0, stream>>>(xb, wT, route);
    k_gemm2<<<dim3(32, 8), 256, 0, stream>>>(route, pT, out);
}

// Round 2
// 93.527 us; speedup vs baseline: 1.7787x; 1.7787x over previous
//
#include <hip/hip_runtime.h>
#include <hip/hip_bf16.h>

// ---- problem constants ----
#define BATCH   4096
#define FEAT    1024
#define NTREES  10
#define NNODES  255
#define NLEAF   256
#define NCLS    1000
#define KTOT    (NTREES*NLEAF) // 2560 = GEMM2 K

typedef __attribute__((ext_vector_type(8))) short  bf16x8;
typedef __attribute__((ext_vector_type(4))) float  f32x4;

// workspace layout (bytes)
#define OFF_XB 0u                         // x bf16 [4096][1024]
#define OFF_WT 8388608u                   // wT bf16 [10][256][1024]
#define OFF_PT 13631488u                  // pT bf16 [1024][2560]
#define OFF_RT 18874368u                  // route bf16 [4096][2560]

#define WAITVM(N) asm volatile("s_waitcnt vmcnt(" #N ")" ::: "memory")
#define WAITLGKM() asm volatile("s_waitcnt lgkmcnt(0)" ::: "memory")
#define BAR() __builtin_amdgcn_s_barrier()

__device__ __forceinline__ void load_lds16(const void* g, void* l) {
    __builtin_amdgcn_global_load_lds(
        (const __attribute__((address_space(1))) unsigned int*)g,
        (__attribute__((address_space(3))) unsigned int*)l, 16, 0, 0);
}

// ---------------- conversion kernels (unchanged) ----------------

__global__ void k_cvt_x(const float* __restrict__ x, __hip_bfloat16* __restrict__ xb) {
    int i = blockIdx.x * 256 + threadIdx.x;
    float4 v = reinterpret_cast<const float4*>(x)[i];
    union { ushort4 u; __hip_bfloat16 h[4]; } o;
    o.h[0] = __float2bfloat16(v.x);
    o.h[1] = __float2bfloat16(v.y);
    o.h[2] = __float2bfloat16(v.z);
    o.h[3] = __float2bfloat16(v.w);
    reinterpret_cast<ushort4*>(xb)[i] = o.u;
}

__global__ void k_cvt_w(const float* __restrict__ w, __hip_bfloat16* __restrict__ wT) {
    __shared__ float tile[32][33];
    int t  = blockIdx.z;
    int nb = blockIdx.x * 32;
    int fb = blockIdx.y * 32;
    int tx = threadIdx.x & 31, ty = threadIdx.x >> 5;
#pragma unroll
    for (int j = 0; j < 4; ++j) {
        int f = fb + ty + j * 8;
        int n = nb + tx;
        float v = (n < NNODES) ? w[((size_t)t * FEAT + f) * NNODES + n] : 0.f;
        tile[ty + j * 8][tx] = v;
    }
    __syncthreads();
#pragma unroll
    for (int j = 0; j < 4; ++j) {
        int n = nb + ty + j * 8;
        int f = fb + tx;
        wT[((size_t)t * NLEAF + n) * FEAT + f] = __float2bfloat16(tile[tx][ty + j * 8]);
    }
}

__global__ void k_cvt_p(const float* __restrict__ p, __hip_bfloat16* __restrict__ pT) {
    __shared__ float tile[32][33];
    int cb = blockIdx.x * 32;
    int kb = blockIdx.y * 32;
    int tx = threadIdx.x & 31, ty = threadIdx.x >> 5;
#pragma unroll
    for (int j = 0; j < 4; ++j) {
        int k = kb + ty + j * 8;
        int c = cb + tx;
        float v = (c < NCLS) ? p[(size_t)k * NCLS + c] * 0.1f : 0.f;
        tile[ty + j * 8][tx] = v;
    }
    __syncthreads();
#pragma unroll
    for (int j = 0; j < 4; ++j) {
        int c = cb + ty + j * 8;
        int k = kb + tx;
        pT[(size_t)c * KTOT + k] = __float2bfloat16(tile[tx][ty + j * 8]);
    }
}

// ---------------- GEMM1 + sigmoid + routing ----------------
// tile 64(M) x 256(N=one tree), BK=64, 512 thr = 8 waves (2M x 4N), wave 32x64
// dbuf LDS: 2 x (A 8KB + B 32KB) = 80KB -> 2 blocks/CU.
// XOR-swizzled LDS (pre-swizzled global src, swizzled frag read).
__global__ __launch_bounds__(512, 4) void k_gemm1_route(
        const __hip_bfloat16* __restrict__ xb,
        const __hip_bfloat16* __restrict__ wT,
        __hip_bfloat16* __restrict__ route) {
    __shared__ __align__(16) char smem[81920];

    // XCD-chunked swizzle: 640 blocks, 80/XCD; same-tree blocks share an XCD L2
    int wg = blockIdx.y * 64 + blockIdx.x;          // hw linear id
    int sw = (wg & 7) * 80 + (wg >> 3);             // bijective (640 % 8 == 0)
    const int bm = sw & 63;
    const int tr = sw >> 6;

    const int tid = threadIdx.x;
    const int lane = tid & 63, wid = tid >> 6;
    const int wm = wid >> 2, wn = wid & 3;          // 2 x 4 waves
    const int r8 = lane >> 3, c8 = lane & 7;        // staging lane decomp

    f32x4 acc[2][4] = {};

    const __hip_bfloat16* Ag = xb + (size_t)(bm * 64) * FEAT;
    const __hip_bfloat16* Bg = wT + (size_t)tr * NLEAF * FEAT;

    const int NT = FEAT / 64;                       // 16
    int cur = 0;

    // ---- stage tile it into buffer b ----
    auto stage = [&](int b, int k0) {
        const int bufA = b * 40960;
        const int bufB = bufA + 8192;
        // A: 64 rows x 64 cols = 8KB -> 1 instr/wave
        load_lds16(Ag + (size_t)(wid * 8 + r8) * FEAT + k0 + ((c8 ^ r8) << 3),
                   smem + bufA + wid * 1024);
        // B: 256 rows x 64 cols = 32KB -> 4 instr/wave
#pragma unroll
        for (int q = 0; q < 4; ++q) {
            int row = (wid * 4 + q) * 8 + r8;
            load_lds16(Bg + (size_t)row * FEAT + k0 + ((c8 ^ r8) << 3),
                       smem + bufB + (wid * 4 + q) * 1024);
        }
    };

    stage(0, 0);                                    // prologue: 5 loads in flight

    for (int it = 0; it < NT; ++it) {
        if (it + 1 < NT) {
            stage(cur ^ 1, (it + 1) * 64);          // +5 newer loads
            WAITVM(5);                              // oldest tile landed
        } else {
            WAITVM(0);
        }
        BAR();                                      // all waves' tile visible

        const char* As = smem + cur * 40960;
        const char* Bs = As + 8192;
#pragma unroll
        for (int ks = 0; ks < 2; ++ks) {
            const int s = ks * 4 + (lane >> 4);
            const int x7 = lane & 7;
            bf16x8 a[2], b[4];
#pragma unroll
            for (int mf = 0; mf < 2; ++mf) {
                int row = wm * 32 + mf * 16 + (lane & 15);
                a[mf] = *(const bf16x8*)(As + row * 128 + ((s ^ x7) << 4));
            }
#pragma unroll
            for (int nf = 0; nf < 4; ++nf) {
                int row = wn * 64 + nf * 16 + (lane & 15);
                b[nf] = *(const bf16x8*)(Bs + row * 128 + ((s ^ x7) << 4));
            }
#pragma unroll
            for (int mf = 0; mf < 2; ++mf)
#pragma unroll
                for (int nf = 0; nf < 4; ++nf)
                    acc[mf][nf] = __builtin_amdgcn_mfma_f32_16x16x32_bf16(
                        a[mf], b[nf], acc[mf][nf], 0, 0, 0);
        }
        WAITLGKM();                                 // my reads retired
        BAR();                                      // safe to overwrite cur
        cur ^= 1;
    }

    // ---- epilogue: sigmoid -> Ds[64][257] fp32 -> routing -> route bf16 ----
    float* Ds = (float*)smem;
#pragma unroll
    for (int mf = 0; mf < 2; ++mf)
#pragma unroll
        for (int nf = 0; nf < 4; ++nf)
#pragma unroll
            for (int r = 0; r < 4; ++r) {
                int row = wm * 32 + mf * 16 + (lane >> 4) * 4 + r;
                int col = wn * 64 + nf * 16 + (lane & 15);
                float z = acc[mf][nf][r];
                Ds[row * 257 + col] = 1.f / (1.f + __expf(-z));
            }
    __syncthreads();
#pragma unroll
    for (int rr = 0; rr < 8; ++rr) {
        int row = wid * 8 + rr;                     // 0..63
#pragma unroll
        for (int cc = 0; cc < 4; ++cc) {
            int leaf = cc * 64 + lane;
            float prod = 1.f;
#pragma unroll
            for (int l = 0; l < 8; ++l) {
                int nidx = (1 << l) - 1 + (leaf >> (8 - l));
                float v = Ds[row * 257 + nidx];
                prod *= (((leaf >> (7 - l)) & 1) == 0) ? v : (1.f - v);
            }
            int bb = bm * 64 + row;
            route[(size_t)bb * KTOT + tr * NLEAF + leaf] = __float2bfloat16(prod);
        }
    }
}

// ---------------- GEMM2 + clip ----------------
// tile 64(M) x 128(N), K=2560, BK=64; 512 thr = 8 waves (2M x 4N), wave 32x32
// dbuf LDS: 2 x (A 8KB + B 16KB) = 48KB -> grid 512 -> 2 blocks/CU.
__global__ __launch_bounds__(512, 4) void k_gemm2(
        const __hip_bfloat16* __restrict__ route,
        const __hip_bfloat16* __restrict__ pT,
        float* __restrict__ out) {
    __shared__ __align__(16) char smem[49152];

    int wg = blockIdx.y * 64 + blockIdx.x;          // 512 blocks
    int sw = (wg & 7) * 64 + (wg >> 3);             // bijective (512 % 8 == 0)
    const int bm = sw & 63;                         // 64 M-tiles
    const int bn = sw >> 6;                         // 8 N-tiles

    const int tid = threadIdx.x;
    const int lane = tid & 63, wid = tid >> 6;
    const int wm = wid >> 2, wn = wid & 3;
    const int r8 = lane >> 3, c8 = lane & 7;

    f32x4 acc[2][2] = {};

    const __hip_bfloat16* Ag = route + (size_t)(bm * 64) * KTOT;
    const __hip_bfloat16* Bg = pT + (size_t)(bn * 128) * KTOT;

    const int NT = KTOT / 64;                       // 40
    int cur = 0;

    auto stage = [&](int b, int k0) {
        const int bufA = b * 24576;
        const int bufB = bufA + 8192;
        // A: 64 rows -> 1 instr/wave
        load_lds16(Ag + (size_t)(wid * 8 + r8) * KTOT + k0 + ((c8 ^ r8) << 3),
                   smem + bufA + wid * 1024);
        // B: 128 rows -> 2 instr/wave
#pragma unroll
        for (int q = 0; q < 2; ++q) {
            int row = (wid * 2 + q) * 8 + r8;
            load_lds16(Bg + (size_t)row * KTOT + k0 + ((c8 ^ r8) << 3),
                       smem + bufB + (wid * 2 + q) * 1024);
        }
    };

    stage(0, 0);

    for (int it = 0; it < NT; ++it) {
        if (it + 1 < NT) {
            stage(cur ^ 1, (it + 1) * 64);
            WAITVM(3);
        } else {
            WAITVM(0);
        }
        BAR();

        const char* As = smem + cur * 24576;
        const char* Bs = As + 8192;
#pragma unroll
        for (int ks = 0; ks < 2; ++ks) {
            const int s = ks * 4 + (lane >> 4);
            const int x7 = lane & 7;
            bf16x8 a[2], b[2];
#pragma unroll
            for (int mf = 0; mf < 2; ++mf) {
                int row = wm * 32 + mf * 16 + (lane & 15);
                a[mf] = *(const bf16x8*)(As + row * 128 + ((s ^ x7) << 4));
            }
#pragma unroll
            for (int nf = 0; nf < 2; ++nf) {
                int row = wn * 32 + nf * 16 + (lane & 15);
                b[nf] = *(const bf16x8*)(Bs + row * 128 + ((s ^ x7) << 4));
            }
#pragma unroll
            for (int mf = 0; mf < 2; ++mf)
#pragma unroll
                for (int nf = 0; nf < 2; ++nf)
                    acc[mf][nf] = __builtin_amdgcn_mfma_f32_16x16x32_bf16(
                        a[mf], b[nf], acc[mf][nf], 0, 0, 0);
        }
        WAITLGKM();
        BAR();
        cur ^= 1;
    }

    // clip + masked store (output is 1000 wide)
#pragma unroll
    for (int mf = 0; mf < 2; ++mf)
#pragma unroll
        for (int nf = 0; nf < 2; ++nf)
#pragma unroll
            for (int r = 0; r < 4; ++r) {
                int row = bm * 64 + wm * 32 + mf * 16 + (lane >> 4) * 4 + r;
                int col = bn * 128 + wn * 32 + nf * 16 + (lane & 15);
                if (col < NCLS) {
                    float v = acc[mf][nf][r];
                    v = fminf(fmaxf(v, 0.f), 1.f);
                    out[(size_t)row * NCLS + col] = v;
                }
            }
}

extern "C" void kernel_launch(void* const* d_in, const int* in_sizes, int n_in,
                              void* d_out, int out_size, void* d_ws, size_t ws_size,
                              hipStream_t stream) {
    const float* x = (const float*)d_in[0];
    const float* w = (const float*)d_in[1];
    const float* p = (const float*)d_in[2];
    float* out = (float*)d_out;
    char* ws = (char*)d_ws;

    __hip_bfloat16* xb    = (__hip_bfloat16*)(ws + OFF_XB);
    __hip_bfloat16* wT    = (__hip_bfloat16*)(ws + OFF_WT);
    __hip_bfloat16* pT    = (__hip_bfloat16*)(ws + OFF_PT);
    __hip_bfloat16* route = (__hip_bfloat16*)(ws + OFF_RT);

    k_cvt_x<<<4096, 256, 0, stream>>>(x, xb);
    k_cvt_w<<<dim3(8, 32, 10), 256, 0, stream>>>(w, wT);
    k_cvt_p<<<dim3(32, 80), 256, 0, stream>>>(p, pT);
    k_gemm1_route<<<dim3(64, 10), 512, 0, stream>>>(xb, wT, route);
    k_gemm2<<<dim3(64, 8), 512, 0, stream>>>(route, pT, out);
}